// Round 1
// baseline (5199.103 us; speedup 1.0000x reference)
//
#include <hip/hip_runtime.h>
#include <math.h>

// decoderRNN: attention LSTM caption decoder, teacher-forced.
// B=64 L=49 F=2048 T=32 V=15000 E=H=A=512
#define B_ 64
#define L_ 49
#define F_DIM 2048
#define T_ 32
#define V_ 15000
#define E_ 512
#define H_ 512
#define A_ 512

// ---------------- generic tiled f32 GEMM: C[M,N] = A[M,K] @ W[N,K]^T (+bias) ----------------
// BM=64, BN=64, BK=16, 256 threads, 4x4 micro-tile per thread.
// - W split: rows [0,N0) from W0 (stride ldw0), rows [N0,N) from W1 (stride ldw1)
// - bias0 for n<N0, bias1 for n>=N0 (indexed n-N0), biasX added for all n
// - split-K via gridDim.z: chunk z computes K-range z*(K/Z)..; output offset z*M*ldc (no bias)
// - permT!=0: store row = (m&63)*permT + (m>>6)  (maps [t*64+b] -> [b*T+t])
__global__ __launch_bounds__(256)
void gemm64(const float* __restrict__ A, int lda,
            const float* __restrict__ W0, int ldw0, int N0,
            const float* __restrict__ W1, int ldw1,
            const float* __restrict__ bias0, const float* __restrict__ bias1,
            const float* __restrict__ biasX,
            float* __restrict__ C, int ldc,
            int N, int K, int permT)
{
    __shared__ float As[16][64];
    __shared__ float Ws[16][64];

    const int tid = threadIdx.x;
    const int m0  = blockIdx.x * 64;
    const int n0  = blockIdx.y * 64;

    const int nkb     = gridDim.z;
    const int klen    = K / nkb;
    const int k_start = blockIdx.z * klen;
    const int k_end   = k_start + klen;

    float* Cb = C;
    if (nkb > 1) Cb += (size_t)blockIdx.z * (size_t)gridDim.x * 64 * (size_t)ldc;

    // loader mapping: each thread loads one float4 (lr = row-in-tile, kq = k-quad)
    const int lr = tid >> 2;
    const int kq = tid & 3;

    const int n_abs = n0 + lr;
    const bool wvalid = (n_abs < N);
    const float* wrow = nullptr;
    if (wvalid)
        wrow = (n_abs < N0) ? (W0 + (size_t)n_abs * ldw0)
                            : (W1 + (size_t)(n_abs - N0) * ldw1);
    const float* arow = A + (size_t)(m0 + lr) * lda;

    const int ty = tid >> 4;   // 0..15 -> m micro
    const int tx = tid & 15;   // 0..15 -> n micro

    float acc[4][4] = {{0.f}};

    for (int kc = k_start; kc < k_end; kc += 16) {
        float4 av = *reinterpret_cast<const float4*>(arow + kc + kq * 4);
        float4 wv = make_float4(0.f, 0.f, 0.f, 0.f);
        if (wvalid)
            wv = *reinterpret_cast<const float4*>(wrow + kc + kq * 4);

        __syncthreads();
        As[kq * 4 + 0][lr] = av.x;
        As[kq * 4 + 1][lr] = av.y;
        As[kq * 4 + 2][lr] = av.z;
        As[kq * 4 + 3][lr] = av.w;
        Ws[kq * 4 + 0][lr] = wv.x;
        Ws[kq * 4 + 1][lr] = wv.y;
        Ws[kq * 4 + 2][lr] = wv.z;
        Ws[kq * 4 + 3][lr] = wv.w;
        __syncthreads();

        #pragma unroll
        for (int kk = 0; kk < 16; ++kk) {
            const float4 a4 = *reinterpret_cast<const float4*>(&As[kk][ty * 4]);
            const float4 w4 = *reinterpret_cast<const float4*>(&Ws[kk][tx * 4]);
            const float aa[4] = {a4.x, a4.y, a4.z, a4.w};
            const float ww[4] = {w4.x, w4.y, w4.z, w4.w};
            #pragma unroll
            for (int i = 0; i < 4; ++i)
                #pragma unroll
                for (int j = 0; j < 4; ++j)
                    acc[i][j] = fmaf(aa[i], ww[j], acc[i][j]);
        }
    }

    #pragma unroll
    for (int i = 0; i < 4; ++i) {
        const int m = m0 + ty * 4 + i;
        #pragma unroll
        for (int j = 0; j < 4; ++j) {
            const int n = n0 + tx * 4 + j;
            if (n >= N) continue;
            float v = acc[i][j];
            if (nkb == 1) {
                if (bias0 && n < N0) v += bias0[n];
                if (bias1 && n >= N0) v += bias1[n - N0];
                if (biasX) v += biasX[n];
            }
            const size_t row = permT ? ((size_t)(m & 63) * permT + (size_t)(m >> 6))
                                     : (size_t)m;
            Cb[row * (size_t)ldc + n] = v;
        }
    }
}

// ---------------- mean over L ----------------
__global__ __launch_bounds__(256)
void k_mean(const float* __restrict__ feat, float* __restrict__ mean_f)
{
    const int idx = blockIdx.x * 256 + threadIdx.x;   // b*2048 + f
    const int b = idx >> 11;
    const int f = idx & 2047;
    const float* p = feat + (size_t)b * L_ * F_DIM + f;
    float s = 0.f;
    #pragma unroll 7
    for (int l = 0; l < L_; ++l) s += p[(size_t)l * F_DIM];
    mean_f[idx] = s * (1.0f / 49.0f);
}

// ---------------- embedding gather: emb_seq[(t*64+b), e] = table[captions[b,t], e] ----------------
__global__ __launch_bounds__(256)
void k_embgather(const float* __restrict__ table, const int* __restrict__ caps,
                 float* __restrict__ emb_seq)
{
    const int idx = blockIdx.x * 256 + threadIdx.x;   // row*512 + e
    const int e   = idx & 511;
    const int row = idx >> 9;
    const int t   = row >> 6;
    const int b   = row & 63;
    const int tok = caps[b * T_ + t];
    emb_seq[idx] = table[(size_t)tok * E_ + e];
}

// ---------------- attention: scores -> softmax -> context (one block per batch) ----------------
__global__ __launch_bounds__(256)
void k_attn(const float* __restrict__ att1, const float* __restrict__ att2gh,
            const float* __restrict__ feat, const float* __restrict__ v_w,
            const float* __restrict__ v_b, float* __restrict__ context)
{
    __shared__ float a2[A_];
    __shared__ float sc[L_];

    const int b   = blockIdx.x;
    const int tid = threadIdx.x;

    for (int i = tid; i < A_; i += 256) a2[i] = att2gh[(size_t)b * 2560 + i];
    __syncthreads();

    const int wave = tid >> 6;
    const int lane = tid & 63;

    for (int l = wave; l < L_; l += 4) {
        const float* a1 = att1 + ((size_t)b * L_ + l) * A_;
        float s = 0.f;
        for (int a = lane; a < A_; a += 64)
            s += tanhf(a1[a] + a2[a]) * v_w[a];
        #pragma unroll
        for (int off = 32; off > 0; off >>= 1) s += __shfl_down(s, off);
        if (lane == 0) sc[l] = s + v_b[0];
    }
    __syncthreads();

    if (tid < 64) {
        float v = (lane < L_) ? sc[lane] : -3.0e38f;
        float mx = v;
        #pragma unroll
        for (int off = 32; off > 0; off >>= 1) mx = fmaxf(mx, __shfl_xor(mx, off));
        float e = (lane < L_) ? __expf(v - mx) : 0.f;
        float sum = e;
        #pragma unroll
        for (int off = 32; off > 0; off >>= 1) sum += __shfl_xor(sum, off);
        if (lane < L_) sc[lane] = e / sum;
    }
    __syncthreads();

    for (int f = tid; f < F_DIM; f += 256) {
        const float* fp = feat + (size_t)b * L_ * F_DIM + f;
        float acc = 0.f;
        #pragma unroll 7
        for (int l = 0; l < L_; ++l) acc += sc[l] * fp[(size_t)l * F_DIM];
        context[(size_t)b * F_DIM + f] = acc;
    }
}

// ---------------- LSTM pointwise: sum split-K partials + g_emb + gh, gate, update state ----------------
__global__ __launch_bounds__(256)
void k_pw(const float* __restrict__ part, const float* __restrict__ g_emb_t,
          const float* __restrict__ att2gh, float* __restrict__ c_st,
          float* __restrict__ h_next, float* __restrict__ h_hist_t)
{
    const int idx = blockIdx.x * 256 + threadIdx.x;   // b*512 + n
    const int b = idx >> 9;
    const int n = idx & 511;

    float gi = 0.f, gf = 0.f, gg = 0.f, go = 0.f;
    const float* p = part + (size_t)b * 2048;
    #pragma unroll
    for (int kb = 0; kb < 8; ++kb) {
        const float* q = p + (size_t)kb * 64 * 2048;
        gi += q[n];
        gf += q[n + 512];
        gg += q[n + 1024];
        go += q[n + 1536];
    }
    const float* ge = g_emb_t + (size_t)b * 2048;
    const float* gh = att2gh + (size_t)b * 2560 + 512;
    gi += ge[n]        + gh[n];
    gf += ge[n + 512]  + gh[n + 512];
    gg += ge[n + 1024] + gh[n + 1024];
    go += ge[n + 1536] + gh[n + 1536];

    const float i = 1.f / (1.f + __expf(-gi));
    const float f = 1.f / (1.f + __expf(-gf));
    const float g = tanhf(gg);
    const float o = 1.f / (1.f + __expf(-go));

    const float c = f * c_st[idx] + i * g;
    const float h = o * tanhf(c);

    c_st[idx]     = c;
    h_next[idx]   = h;
    h_hist_t[idx] = h;
}

extern "C" void kernel_launch(void* const* d_in, const int* in_sizes, int n_in,
                              void* d_out, int out_size, void* d_ws, size_t ws_size,
                              hipStream_t stream)
{
    const float* features = (const float*)d_in[0];
    const int*   captions = (const int*)d_in[1];
    // d_in[2] = force_prob (==1, teacher forcing) -- unused
    const float* init_h_W = (const float*)d_in[3];
    const float* init_h_b = (const float*)d_in[4];
    const float* init_c_W = (const float*)d_in[5];
    const float* init_c_b = (const float*)d_in[6];
    const float* W_a_W    = (const float*)d_in[7];
    const float* W_a_b    = (const float*)d_in[8];
    const float* U_a_W    = (const float*)d_in[9];
    const float* U_a_b    = (const float*)d_in[10];
    const float* v_a_W    = (const float*)d_in[11];
    const float* v_a_b    = (const float*)d_in[12];
    const float* embed    = (const float*)d_in[13];
    const float* W_ih     = (const float*)d_in[14];
    const float* W_hh     = (const float*)d_in[15];
    const float* b_ih     = (const float*)d_in[16];
    const float* b_hh     = (const float*)d_in[17];
    const float* fc_W     = (const float*)d_in[18];
    const float* fc_b     = (const float*)d_in[19];
    float* out = (float*)d_out;

    // workspace layout (floats); every buffer is fully written before read each call
    float* ws       = (float*)d_ws;
    float* mean_f   = ws;                    // 64*2048           = 131072
    float* hA       = mean_f + 131072;       // 64*512            = 32768
    float* hB       = hA + 32768;            // 32768
    float* c_st     = hB + 32768;            // 32768
    float* att2gh   = c_st + 32768;          // 64*2560           = 163840
    float* context  = att2gh + 163840;       // 64*2048           = 131072
    float* att1     = context + 131072;      // 3136*512          = 1605632
    float* emb_seq  = att1 + 1605632;        // 2048*512          = 1048576
    float* g_emb    = emb_seq + 1048576;     // 2048*2048         = 4194304
    float* gpart    = g_emb + 4194304;       // 8*64*2048         = 1048576
    float* h_hist   = gpart + 1048576;       // 2048*512          = 1048576
    // total ~9.47M floats (~38 MB)

    // ---- prologue (all parallel-friendly, off the recurrence critical path) ----
    k_mean<<<512, 256, 0, stream>>>(features, mean_f);

    // h0 = mean_f @ init_h_W^T + b ; c0 likewise
    gemm64<<<dim3(1, 8, 1), 256, 0, stream>>>(mean_f, F_DIM, init_h_W, F_DIM, H_,
                                              nullptr, 0, init_h_b, nullptr, nullptr,
                                              hA, H_, H_, F_DIM, 0);
    gemm64<<<dim3(1, 8, 1), 256, 0, stream>>>(mean_f, F_DIM, init_c_W, F_DIM, H_,
                                              nullptr, 0, init_c_b, nullptr, nullptr,
                                              c_st, H_, H_, F_DIM, 0);

    // att1[b*49+l, a] = features @ W_a^T + b_a
    gemm64<<<dim3(49, 8, 1), 256, 0, stream>>>(features, F_DIM, W_a_W, F_DIM, A_,
                                               nullptr, 0, W_a_b, nullptr, nullptr,
                                               att1, A_, A_, F_DIM, 0);

    // embedding gather for all T steps, then its gates contribution (+both biases)
    k_embgather<<<4096, 256, 0, stream>>>(embed, captions, emb_seq);
    gemm64<<<dim3(32, 32, 1), 256, 0, stream>>>(emb_seq, E_, W_ih, E_ + F_DIM, 4 * H_,
                                                nullptr, 0, b_ih, nullptr, b_hh,
                                                g_emb, 4 * H_, 4 * H_, E_, 0);

    // ---- recurrence: 32 sequential steps, 4 kernels each ----
    float* hc = hA;
    float* hn = hB;
    for (int t = 0; t < T_; ++t) {
        // att2gh[b, 0:512] = h @ U_a^T + U_a_b ; att2gh[b, 512:2560] = h @ W_hh^T
        gemm64<<<dim3(1, 40, 1), 256, 0, stream>>>(hc, H_, U_a_W, H_, A_,
                                                   W_hh, H_, U_a_b, nullptr, nullptr,
                                                   att2gh, A_ + 4 * H_, A_ + 4 * H_, H_, 0);

        k_attn<<<64, 256, 0, stream>>>(att1, att2gh, features, v_a_W, v_a_b, context);

        // gates partials: context @ W_ih[:,512:2560]^T  (split-K x8)
        gemm64<<<dim3(1, 32, 8), 256, 0, stream>>>(context, F_DIM, W_ih + E_, E_ + F_DIM, 4 * H_,
                                                   nullptr, 0, nullptr, nullptr, nullptr,
                                                   gpart, 4 * H_, 4 * H_, F_DIM, 0);

        k_pw<<<128, 256, 0, stream>>>(gpart, g_emb + (size_t)t * 64 * 2048, att2gh,
                                      c_st, hn, h_hist + (size_t)t * 64 * 512);

        float* tmp = hc; hc = hn; hn = tmp;
    }

    // ---- all logits at once: [T*B, H] @ fc_W^T + fc_b, permuted store to [B,T,V] ----
    gemm64<<<dim3(32, 235, 1), 256, 0, stream>>>(h_hist, H_, fc_W, H_, V_,
                                                 nullptr, 0, fc_b, nullptr, nullptr,
                                                 out, V_, V_, H_, T_);
}

// Round 2
// 3041.364 us; speedup vs baseline: 1.7095x; 1.7095x over previous
//
#include <hip/hip_runtime.h>
#include <math.h>

// decoderRNN: attention LSTM caption decoder, teacher-forced.
// B=64 L=49 F=2048 T=32 V=15000 E=H=A=512
#define B_ 64
#define L_ 49
#define F_DIM 2048
#define T_ 32
#define V_ 15000
#define E_ 512
#define H_ 512
#define A_ 512

typedef __attribute__((ext_vector_type(8))) short short8;
typedef __attribute__((ext_vector_type(4))) float f32x4;

__device__ __forceinline__ unsigned short f2b(float x) {
    union { float f; unsigned int u; } v; v.f = x;
    unsigned int r = v.u + 0x7FFF + ((v.u >> 16) & 1);
    return (unsigned short)(r >> 16);
}

// ---------------- f32 -> bf16 cast, row-strided ----------------
__global__ __launch_bounds__(256)
void k_cast(const float* __restrict__ src, unsigned short* __restrict__ dst,
            int cols, int src_stride)
{
    const int r  = blockIdx.y;
    const int c4 = blockIdx.x * 256 + threadIdx.x;
    if (c4 * 4 >= cols) return;
    float4 v = *reinterpret_cast<const float4*>(src + (size_t)r * src_stride + c4 * 4);
    ushort4 o;
    o.x = f2b(v.x); o.y = f2b(v.y); o.z = f2b(v.z); o.w = f2b(v.w);
    *reinterpret_cast<ushort4*>(dst + (size_t)r * cols + c4 * 4) = o;
}

// ---------------- bf16 MFMA GEMM: C[M,N] = A[M,K] @ W[N,K]^T (+bias) ----------------
// 128x128 tile, BK=32, 4 waves (2x2), each wave 64x64 = 4x4 frags of 16x16x32.
// permT!=0: store row = (m&63)*permT + (m>>6)   ([t*64+b] -> [b*T+t])
#define LDSW 40   // shorts per LDS row: 32 data + 8 pad (bank-spread)
__global__ __launch_bounds__(256)
void gemm_mfma(const unsigned short* __restrict__ A, int lda,
               const unsigned short* __restrict__ W, int ldw,
               const float* __restrict__ bias,
               float* __restrict__ C, int ldc,
               int M, int N, int K, int permT)
{
    __shared__ unsigned short As[128 * LDSW];
    __shared__ unsigned short Ws[128 * LDSW];

    const int tid  = threadIdx.x;
    const int m0   = blockIdx.x * 128;
    const int n0   = blockIdx.y * 128;
    const int wave = tid >> 6;
    const int lane = tid & 63;
    const int wr   = (wave >> 1) * 64;   // wave row offset in tile
    const int wc   = (wave & 1) * 64;    // wave col offset in tile

    f32x4 acc[4][4];
    #pragma unroll
    for (int i = 0; i < 4; ++i)
        #pragma unroll
        for (int j = 0; j < 4; ++j)
            acc[i][j] = (f32x4)(0.f);

    const int fr = lane & 15;            // fragment row/col within 16
    const int fk = (lane >> 4) * 8;      // k-offset of this lane's 8 elements

    for (int kc = 0; kc < K; kc += 32) {
        // stage 128x32 of A and W (each thread: 2 x 16B per matrix)
        float4 av[2], wv[2];
        #pragma unroll
        for (int i = 0; i < 2; ++i) {
            const int idx = tid + i * 256;
            const int row = idx >> 2;
            const int seg = idx & 3;
            av[i] = make_float4(0.f, 0.f, 0.f, 0.f);
            wv[i] = make_float4(0.f, 0.f, 0.f, 0.f);
            if (m0 + row < M)
                av[i] = *reinterpret_cast<const float4*>(A + (size_t)(m0 + row) * lda + kc + seg * 8);
            if (n0 + row < N)
                wv[i] = *reinterpret_cast<const float4*>(W + (size_t)(n0 + row) * ldw + kc + seg * 8);
        }
        __syncthreads();
        #pragma unroll
        for (int i = 0; i < 2; ++i) {
            const int idx = tid + i * 256;
            const int row = idx >> 2;
            const int seg = idx & 3;
            *reinterpret_cast<float4*>(&As[row * LDSW + seg * 8]) = av[i];
            *reinterpret_cast<float4*>(&Ws[row * LDSW + seg * 8]) = wv[i];
        }
        __syncthreads();

        short8 afr[4], bfr[4];
        #pragma unroll
        for (int mf = 0; mf < 4; ++mf)
            afr[mf] = *reinterpret_cast<const short8*>(&As[(wr + mf * 16 + fr) * LDSW + fk]);
        #pragma unroll
        for (int nf = 0; nf < 4; ++nf)
            bfr[nf] = *reinterpret_cast<const short8*>(&Ws[(wc + nf * 16 + fr) * LDSW + fk]);

        #pragma unroll
        for (int mf = 0; mf < 4; ++mf)
            #pragma unroll
            for (int nf = 0; nf < 4; ++nf)
                acc[mf][nf] = __builtin_amdgcn_mfma_f32_16x16x32_bf16(
                    afr[mf], bfr[nf], acc[mf][nf], 0, 0, 0);
    }

    // store: D[(lane>>4)*4 + r][lane&15] per 16x16 fragment
    const int cr = (lane >> 4) * 4;
    const int cc = lane & 15;
    #pragma unroll
    for (int nf = 0; nf < 4; ++nf) {
        const int n = n0 + wc + nf * 16 + cc;
        if (n >= N) continue;
        const float bv = bias ? bias[n] : 0.f;
        #pragma unroll
        for (int mf = 0; mf < 4; ++mf) {
            #pragma unroll
            for (int r = 0; r < 4; ++r) {
                const int m = m0 + wr + mf * 16 + cr + r;
                if (m >= M) continue;
                const size_t row = permT ? ((size_t)(m & 63) * permT + (size_t)(m >> 6))
                                         : (size_t)m;
                C[row * (size_t)ldc + n] = acc[mf][nf][r] + bv;
            }
        }
    }
}

// ---------------- generic tiled f32 GEMM: C[M,N] = A[M,K] @ W[N,K]^T (+bias) ----------------
__global__ __launch_bounds__(256)
void gemm64(const float* __restrict__ A, int lda,
            const float* __restrict__ W0, int ldw0, int N0,
            const float* __restrict__ W1, int ldw1,
            const float* __restrict__ bias0, const float* __restrict__ bias1,
            const float* __restrict__ biasX,
            float* __restrict__ C, int ldc,
            int N, int K, int permT)
{
    __shared__ float As[16][64];
    __shared__ float Ws[16][64];

    const int tid = threadIdx.x;
    const int m0  = blockIdx.x * 64;
    const int n0  = blockIdx.y * 64;

    const int nkb     = gridDim.z;
    const int klen    = K / nkb;
    const int k_start = blockIdx.z * klen;
    const int k_end   = k_start + klen;

    float* Cb = C;
    if (nkb > 1) Cb += (size_t)blockIdx.z * (size_t)gridDim.x * 64 * (size_t)ldc;

    const int lr = tid >> 2;
    const int kq = tid & 3;

    const int n_abs = n0 + lr;
    const bool wvalid = (n_abs < N);
    const float* wrow = nullptr;
    if (wvalid)
        wrow = (n_abs < N0) ? (W0 + (size_t)n_abs * ldw0)
                            : (W1 + (size_t)(n_abs - N0) * ldw1);
    const float* arow = A + (size_t)(m0 + lr) * lda;

    const int ty = tid >> 4;
    const int tx = tid & 15;

    float acc[4][4] = {{0.f}};

    for (int kc = k_start; kc < k_end; kc += 16) {
        float4 av = *reinterpret_cast<const float4*>(arow + kc + kq * 4);
        float4 wv = make_float4(0.f, 0.f, 0.f, 0.f);
        if (wvalid)
            wv = *reinterpret_cast<const float4*>(wrow + kc + kq * 4);

        __syncthreads();
        As[kq * 4 + 0][lr] = av.x;
        As[kq * 4 + 1][lr] = av.y;
        As[kq * 4 + 2][lr] = av.z;
        As[kq * 4 + 3][lr] = av.w;
        Ws[kq * 4 + 0][lr] = wv.x;
        Ws[kq * 4 + 1][lr] = wv.y;
        Ws[kq * 4 + 2][lr] = wv.z;
        Ws[kq * 4 + 3][lr] = wv.w;
        __syncthreads();

        #pragma unroll
        for (int kk = 0; kk < 16; ++kk) {
            const float4 a4 = *reinterpret_cast<const float4*>(&As[kk][ty * 4]);
            const float4 w4 = *reinterpret_cast<const float4*>(&Ws[kk][tx * 4]);
            const float aa[4] = {a4.x, a4.y, a4.z, a4.w};
            const float ww[4] = {w4.x, w4.y, w4.z, w4.w};
            #pragma unroll
            for (int i = 0; i < 4; ++i)
                #pragma unroll
                for (int j = 0; j < 4; ++j)
                    acc[i][j] = fmaf(aa[i], ww[j], acc[i][j]);
        }
    }

    #pragma unroll
    for (int i = 0; i < 4; ++i) {
        const int m = m0 + ty * 4 + i;
        #pragma unroll
        for (int j = 0; j < 4; ++j) {
            const int n = n0 + tx * 4 + j;
            if (n >= N) continue;
            float v = acc[i][j];
            if (nkb == 1) {
                if (bias0 && n < N0) v += bias0[n];
                if (bias1 && n >= N0) v += bias1[n - N0];
                if (biasX) v += biasX[n];
            }
            const size_t row = permT ? ((size_t)(m & 63) * permT + (size_t)(m >> 6))
                                     : (size_t)m;
            Cb[row * (size_t)ldc + n] = v;
        }
    }
}

// ---------------- mean over L ----------------
__global__ __launch_bounds__(256)
void k_mean(const float* __restrict__ feat, float* __restrict__ mean_f)
{
    const int idx = blockIdx.x * 256 + threadIdx.x;
    const int b = idx >> 11;
    const int f = idx & 2047;
    const float* p = feat + (size_t)b * L_ * F_DIM + f;
    float s = 0.f;
    #pragma unroll 7
    for (int l = 0; l < L_; ++l) s += p[(size_t)l * F_DIM];
    mean_f[idx] = s * (1.0f / 49.0f);
}

// ---------------- embedding gather ----------------
__global__ __launch_bounds__(256)
void k_embgather(const float* __restrict__ table, const int* __restrict__ caps,
                 float* __restrict__ emb_seq)
{
    const int idx = blockIdx.x * 256 + threadIdx.x;
    const int e   = idx & 511;
    const int row = idx >> 9;
    const int t   = row >> 6;
    const int b   = row & 63;
    const int tok = caps[b * T_ + t];
    emb_seq[idx] = table[(size_t)tok * E_ + e];
}

// ---------------- fused per-step: attention + gates(weighted featW) + LSTM pointwise ----
// grid 128: block = (batch b, half). half owns output dims n in [half*256, half*256+256).
__global__ __launch_bounds__(256)
void k_step(const float* __restrict__ att1,    // [3136,512]
            const float* __restrict__ att2p,   // [4][64][2560] split-K partials
            const float* __restrict__ Uab,     // [512]
            const float* __restrict__ featW,   // [3136,2048]
            const float* __restrict__ gembt,   // [64,2048] (t-th slice)
            const float* __restrict__ v_w, const float* __restrict__ v_b,
            float* __restrict__ c_st, float* __restrict__ h_next,
            float* __restrict__ h_hist_t)
{
    __shared__ float a2[512];
    __shared__ float ghh[1024];   // this half's 4 gate-chunks of h@W_hh^T
    __shared__ float wl[64];
    __shared__ float gates[1024];

    const int b    = blockIdx.x >> 1;
    const int half = blockIdx.x & 1;
    const int tid  = threadIdx.x;

    // sum the 4 split-K partials; a2 gets U_a_b
    for (int i = tid; i < 512; i += 256) {
        float s = Uab[i];
        #pragma unroll
        for (int z = 0; z < 4; ++z) s += att2p[z * 64 * 2560 + b * 2560 + i];
        a2[i] = s;
    }
    for (int i = tid; i < 1024; i += 256) {
        const int grp = i >> 8, j = i & 255;
        const int col = 512 + grp * 512 + half * 256 + j;
        float s = 0.f;
        #pragma unroll
        for (int z = 0; z < 4; ++z) s += att2p[z * 64 * 2560 + b * 2560 + col];
        ghh[i] = s;
    }
    __syncthreads();

    // scores over L=49
    const int wave = tid >> 6;
    const int lane = tid & 63;
    for (int l = wave; l < L_; l += 4) {
        const float* a1 = att1 + (size_t)(b * L_ + l) * 512;
        float s = 0.f;
        for (int a = lane; a < 512; a += 64)
            s += tanhf(a1[a] + a2[a]) * v_w[a];
        #pragma unroll
        for (int off = 32; off > 0; off >>= 1) s += __shfl_down(s, off);
        if (lane == 0) wl[l] = s + v_b[0];
    }
    __syncthreads();

    if (tid < 64) {
        float v = (lane < L_) ? wl[lane] : -3.0e38f;
        float mx = v;
        #pragma unroll
        for (int off = 32; off > 0; off >>= 1) mx = fmaxf(mx, __shfl_xor(mx, off));
        float e = (lane < L_) ? __expf(v - mx) : 0.f;
        float sum = e;
        #pragma unroll
        for (int off = 32; off > 0; off >>= 1) sum += __shfl_xor(sum, off);
        if (lane < L_) wl[lane] = e / sum;
    }
    __syncthreads();

    // gates: each thread one float4 column-chunk
    const int grp = tid >> 6;
    const int j4  = (tid & 63) * 4;
    const int cg  = grp * 512 + half * 256 + j4;     // gate-layout column
    const float* fW = featW + (size_t)(b * L_) * 2048 + cg;
    float4 g4 = *reinterpret_cast<const float4*>(gembt + (size_t)b * 2048 + cg);
    const float4 gh4 = *reinterpret_cast<const float4*>(&ghh[grp * 256 + j4]);
    g4.x += gh4.x; g4.y += gh4.y; g4.z += gh4.z; g4.w += gh4.w;
    #pragma unroll 7
    for (int l = 0; l < L_; ++l) {
        const float w = wl[l];
        const float4 f4 = *reinterpret_cast<const float4*>(fW + (size_t)l * 2048);
        g4.x = fmaf(w, f4.x, g4.x);
        g4.y = fmaf(w, f4.y, g4.y);
        g4.z = fmaf(w, f4.z, g4.z);
        g4.w = fmaf(w, f4.w, g4.w);
    }
    *reinterpret_cast<float4*>(&gates[grp * 256 + j4]) = g4;
    __syncthreads();

    // pointwise LSTM: this half's 256 output dims
    const int j = tid;
    const float gi = gates[j], gf = gates[256 + j], gg = gates[512 + j], go = gates[768 + j];
    const float i = 1.f / (1.f + __expf(-gi));
    const float f = 1.f / (1.f + __expf(-gf));
    const float g = tanhf(gg);
    const float o = 1.f / (1.f + __expf(-go));
    const int n = half * 256 + j;
    const float c = f * c_st[b * 512 + n] + i * g;
    const float h = o * tanhf(c);
    c_st[b * 512 + n]     = c;
    h_next[b * 512 + n]   = h;
    h_hist_t[b * 512 + n] = h;
}

extern "C" void kernel_launch(void* const* d_in, const int* in_sizes, int n_in,
                              void* d_out, int out_size, void* d_ws, size_t ws_size,
                              hipStream_t stream)
{
    const float* features = (const float*)d_in[0];
    const int*   captions = (const int*)d_in[1];
    const float* init_h_W = (const float*)d_in[3];
    const float* init_h_b = (const float*)d_in[4];
    const float* init_c_W = (const float*)d_in[5];
    const float* init_c_b = (const float*)d_in[6];
    const float* W_a_W    = (const float*)d_in[7];
    const float* W_a_b    = (const float*)d_in[8];
    const float* U_a_W    = (const float*)d_in[9];
    const float* U_a_b    = (const float*)d_in[10];
    const float* v_a_W    = (const float*)d_in[11];
    const float* v_a_b    = (const float*)d_in[12];
    const float* embed    = (const float*)d_in[13];
    const float* W_ih     = (const float*)d_in[14];
    const float* W_hh     = (const float*)d_in[15];
    const float* b_ih     = (const float*)d_in[16];
    const float* b_hh     = (const float*)d_in[17];
    const float* fc_W     = (const float*)d_in[18];
    const float* fc_b     = (const float*)d_in[19];
    float* out = (float*)d_out;

    // ---- workspace (floats) ----
    float* ws      = (float*)d_ws;
    float* mean_f  = ws;                   // 131072
    float* hA      = ws + 131072;          // 32768
    float* hB      = ws + 164840 - 1000;   // (see below)  -- avoid typo: compute explicitly
    (void)hB;
    hB             = ws + 163840;          // 32768
    float* c_st    = ws + 196608;          // 32768
    float* att2p   = ws + 229376;          // 4*64*2560 = 655360
    float* att1    = ws + 884736;          // 3136*512  = 1605632
    float* h_hist  = ws + 2490368;         // 2048*512  = 1048576
    float* scratch = ws + 3538944;         // 5308416 (phased union)
    // total 8,847,360 floats = 35.4 MB

    // scratch phases:
    float*          emb_seq = scratch;                               // 2048*512 f32
    unsigned short* feat_bf = (unsigned short*)scratch;              // 3136*2048 bf16
    unsigned short* wihF_bf = (unsigned short*)(scratch + 3211264);  // 2048*2048 bf16
    unsigned short* fcW_bf  = (unsigned short*)scratch;              // 15000*512 bf16
    unsigned short* hh_bf   = (unsigned short*)(scratch + 3840000);  // 2048*512 bf16

    // big dead-by-logits buffers live in d_out (fully overwritten by logits GEMM)
    float* featW = out;                    // 3136*2048 = 6422528
    float* g_emb = out + 6422528;          // 2048*2048 = 4194304

    // ---- prologue ----
    k_mean<<<512, 256, 0, stream>>>(features, mean_f);

    gemm64<<<dim3(1, 8, 1), 256, 0, stream>>>(mean_f, F_DIM, init_h_W, F_DIM, H_,
                                              nullptr, 0, init_h_b, nullptr, nullptr,
                                              hA, H_, H_, F_DIM, 0);
    gemm64<<<dim3(1, 8, 1), 256, 0, stream>>>(mean_f, F_DIM, init_c_W, F_DIM, H_,
                                              nullptr, 0, init_c_b, nullptr, nullptr,
                                              c_st, H_, H_, F_DIM, 0);

    gemm64<<<dim3(49, 8, 1), 256, 0, stream>>>(features, F_DIM, W_a_W, F_DIM, A_,
                                               nullptr, 0, W_a_b, nullptr, nullptr,
                                               att1, A_, A_, F_DIM, 0);

    k_embgather<<<4096, 256, 0, stream>>>(embed, captions, emb_seq);
    gemm64<<<dim3(32, 32, 1), 256, 0, stream>>>(emb_seq, E_, W_ih, E_ + F_DIM, 4 * H_,
                                                nullptr, 0, b_ih, nullptr, b_hh,
                                                g_emb, 4 * H_, 4 * H_, E_, 0);

    // featW = features @ W_ih[:,E:]^T   (bf16 MFMA)
    k_cast<<<dim3(2, 3136), 256, 0, stream>>>(features, feat_bf, 2048, 2048);
    k_cast<<<dim3(2, 2048), 256, 0, stream>>>(W_ih + E_, wihF_bf, 2048, E_ + F_DIM);
    gemm_mfma<<<dim3(25, 16), 256, 0, stream>>>(feat_bf, F_DIM, wihF_bf, F_DIM,
                                                nullptr, featW, 2048,
                                                3136, 2048, F_DIM, 0);

    // ---- recurrence: 2 kernels per step ----
    float* hc = hA;
    float* hn = hB;
    for (int t = 0; t < T_; ++t) {
        gemm64<<<dim3(1, 40, 4), 256, 0, stream>>>(hc, H_, U_a_W, H_, A_,
                                                   W_hh, H_, nullptr, nullptr, nullptr,
                                                   att2p, A_ + 4 * H_, A_ + 4 * H_, H_, 0);

        k_step<<<128, 256, 0, stream>>>(att1, att2p, U_a_b, featW,
                                        g_emb + (size_t)t * 64 * 2048,
                                        v_a_W, v_a_b, c_st, hn,
                                        h_hist + (size_t)t * 64 * 512);

        float* tmp = hc; hc = hn; hn = tmp;
    }

    // ---- logits: [T*B,H] @ fc_W^T + fc_b, bf16 MFMA, permuted store to [B,T,V] ----
    k_cast<<<dim3(1, 2048), 256, 0, stream>>>(h_hist, hh_bf, 512, 512);
    k_cast<<<dim3(1, 15000), 256, 0, stream>>>(fc_W, fcW_bf, 512, 512);
    gemm_mfma<<<dim3(16, 118), 256, 0, stream>>>(hh_bf, H_, fcW_bf, H_,
                                                 fc_b, out, V_,
                                                 2048, V_, H_, T_);
}